// Round 7
// baseline (907.616 us; speedup 1.0000x reference)
//
#include <hip/hip_runtime.h>

#define E 1280
#define H 20
#define L 8192
#define D 64
#define CHUNK 128
#define NCHUNK (L / CHUNK)          // 64
#define NBLK 1280                   // = H * NCHUNK, and exactly 5 blocks/CU

// ---- barrier state layout in d_ws (bytes 0..1023, memset to 0 每 launch) ----
// u32[0]   : ctr1     u32[32] : flag1
// u32[64]  : ctr2     u32[96] : flag2
// u32[128..147] : head_ctr[20]
// float data region starts at byte 1024.

__device__ __forceinline__ void grid_barrier(unsigned* ctr, unsigned* flag) {
    __syncthreads();
    if (threadIdx.x == 0) {
        __threadfence();   // make this block's prior global writes device-visible
        unsigned old = __hip_atomic_fetch_add(ctr, 1u, __ATOMIC_ACQ_REL,
                                              __HIP_MEMORY_SCOPE_AGENT);
        if (old == NBLK - 1) {
            __hip_atomic_store(flag, 1u, __ATOMIC_RELEASE, __HIP_MEMORY_SCOPE_AGENT);
        } else {
            while (__hip_atomic_load(flag, __ATOMIC_ACQUIRE,
                                     __HIP_MEMORY_SCOPE_AGENT) == 0u)
                __builtin_amdgcn_s_sleep(2);
        }
    }
    __syncthreads();
}

__global__ __launch_bounds__(256, 5)   // 5 blocks/CU min -> all 1280 co-resident
void mega_kernel(const float* __restrict__ hs,
                 const float* __restrict__ Wq, const float* __restrict__ bq,
                 const float* __restrict__ Wk,
                 const float* __restrict__ Wv, const float* __restrict__ bv,
                 const float* __restrict__ Wo, const float* __restrict__ bo,
                 const float* __restrict__ kc, const float* __restrict__ vc,
                 const int* __restrict__ pos_p,
                 unsigned* __restrict__ bar,        // barrier state (1KB)
                 float* __restrict__ qkv,           // 3*E
                 float* __restrict__ cmax, float* __restrict__ csum,   // H*NCHUNK
                 float* __restrict__ o_part,        // H*NCHUNK*D
                 float* __restrict__ attn_out,      // E
                 float* __restrict__ out,           // E (d_out[0:E))
                 float* __restrict__ out_k, float* __restrict__ out_v) {
    int tid  = threadIdx.x;
    int wave = tid >> 6;
    int lane = tid & 63;

    __shared__ float s_part[CHUNK][17];
    __shared__ float s_w[CHUNK];
    __shared__ float smax4[4];      // reused as sred in phase 2
    __shared__ float spsum[4];
    __shared__ float sacc[4][D];
    __shared__ unsigned s_last;

    unsigned* ctr1 = bar + 0;
    unsigned* flag1 = bar + 32;
    unsigned* ctr2 = bar + 64;
    unsigned* flag2 = bar + 96;
    unsigned* head_ctr = bar + 128;

    int pos = pos_p[0];

    // ================= phase 0: QKV GEMVs (one row per wave) =================
    {
        int wgid = blockIdx.x * 4 + wave;          // 0..5119, need 0..3839
        if (wgid < 3 * E) {
            int mat = wgid / E;                    // 0=q,1=k,2=v
            int row = wgid - mat * E;
            const float* W = (mat == 0) ? Wq : (mat == 1) ? Wk : Wv;
            const float4* Wrow = (const float4*)(W + (size_t)row * E);
            const float4* h4 = (const float4*)hs;
            float sum = 0.f;
#pragma unroll
            for (int i = 0; i < 5; ++i) {
                int idx = lane + 64 * i;
                float4 w4 = Wrow[idx];
                float4 x4 = h4[idx];
                sum += w4.x * x4.x + w4.y * x4.y + w4.z * x4.z + w4.w * x4.w;
            }
#pragma unroll
            for (int off = 32; off > 0; off >>= 1) sum += __shfl_down(sum, off, 64);
            if (lane == 0) {
                float val;
                if (mat == 0)      val = (sum + bq[row]) * 0.125f;  // scale 64^-0.5
                else if (mat == 1) val = sum;                       // k: no bias
                else               val = sum + bv[row];
                qkv[mat * E + row] = val;
            }
        }
    }
    grid_barrier(ctr1, flag1);

    // ============ phase 1: fused K/V stream + copy + chunk attention ==========
    {
        int job = blockIdx.x;                 // 0..1279
        int h = job >> 6;                     // / NCHUNK
        int c = job & (NCHUNK - 1);
        int cc = tid & 15;
        int rg = tid >> 4;                    // 0..15

        float4 q4  = ((const float4*)qkv)[h * 16 + cc];
        float4 kn4 = ((const float4*)(qkv + E))[h * 16 + cc];
        float4 vn4 = ((const float4*)(qkv + 2 * E))[h * 16 + cc];

        size_t base = ((size_t)h * L + (size_t)c * CHUNK) * D;
        const float* kbase = kc + base;
        const float* vbase = vc + base;
        float* okbase = out_k + base;
        float* ovbase = out_v + base;
        int l0 = c * CHUNK;

        // ---- 1a: stream K (copy + dot partials), V -> registers (copy) ----
        float4 vreg[CHUNK / 16];
#pragma unroll
        for (int it = 0; it < CHUNK / 16; ++it) {
            int r = it * 16 + rg;
            int l = l0 + r;
            float4 k4 = ((const float4*)(kbase + r * D))[cc];
            if (l == pos) k4 = kn4;
            ((float4*)(okbase + r * D))[cc] = k4;
            s_part[r][cc] = k4.x * q4.x + k4.y * q4.y + k4.z * q4.z + k4.w * q4.w;
            float4 v4 = ((const float4*)(vbase + r * D))[cc];
            if (l == pos) v4 = vn4;
            ((float4*)(ovbase + r * D))[cc] = v4;
            vreg[it] = v4;
        }
        __syncthreads();

        // ---- 1b: score reduce + softmax weights ----
        float s = -INFINITY;
        if (tid < CHUNK) {
            float sum = 0.f;
#pragma unroll
            for (int i = 0; i < 16; ++i) sum += s_part[tid][i];
            s = (l0 + tid <= pos) ? sum : -INFINITY;
        }
        float lm = s;
#pragma unroll
        for (int off = 32; off > 0; off >>= 1)
            lm = fmaxf(lm, __shfl_xor(lm, off, 64));
        if (lane == 0) smax4[wave] = lm;
        __syncthreads();
        float m = fmaxf(fmaxf(smax4[0], smax4[1]), fmaxf(smax4[2], smax4[3]));

        float p = 0.f;
        if (tid < CHUNK) {
            p = (s > -1e30f) ? __expf(s - m) : 0.f;
            s_w[tid] = p;
        }
        float ps = p;
#pragma unroll
        for (int off = 32; off > 0; off >>= 1) ps += __shfl_xor(ps, off, 64);
        if (lane == 0) spsum[wave] = ps;
        __syncthreads();

        // ---- 1c: weighted V accumulate from registers ----
        float4 acc = {0.f, 0.f, 0.f, 0.f};
#pragma unroll
        for (int it = 0; it < CHUNK / 16; ++it) {
            int r = it * 16 + rg;
            float w = s_w[r];
            acc.x += w * vreg[it].x; acc.y += w * vreg[it].y;
            acc.z += w * vreg[it].z; acc.w += w * vreg[it].w;
        }
        acc.x += __shfl_xor(acc.x, 16, 64); acc.y += __shfl_xor(acc.y, 16, 64);
        acc.z += __shfl_xor(acc.z, 16, 64); acc.w += __shfl_xor(acc.w, 16, 64);
        acc.x += __shfl_xor(acc.x, 32, 64); acc.y += __shfl_xor(acc.y, 32, 64);
        acc.z += __shfl_xor(acc.z, 32, 64); acc.w += __shfl_xor(acc.w, 32, 64);
        if ((lane >> 4) == 0) ((float4*)&sacc[wave][cc * 4])[0] = acc;
        __syncthreads();
        if (tid < D) {
            float o = sacc[0][tid] + sacc[1][tid] + sacc[2][tid] + sacc[3][tid];
            o_part[((size_t)h * NCHUNK + c) * D + tid] = o;
            if (tid == 0) {
                cmax[h * NCHUNK + c] = m;
                csum[h * NCHUNK + c] = spsum[0] + spsum[1] + spsum[2] + spsum[3];
            }
        }
        __threadfence();
        __syncthreads();

        // ---- 1d: last chunk-block of this head does the cross-chunk combine ----
        if (tid == 0) {
            unsigned old = __hip_atomic_fetch_add(&head_ctr[h], 1u, __ATOMIC_ACQ_REL,
                                                  __HIP_MEMORY_SCOPE_AGENT);
            s_last = (old == NCHUNK - 1) ? 1u : 0u;
        }
        __syncthreads();
        if (s_last && tid < D) {
            float mh = -INFINITY;
#pragma unroll 8
            for (int cj = 0; cj < NCHUNK; ++cj)
                mh = fmaxf(mh, cmax[h * NCHUNK + cj]);
            float denom = 0.f, o = 0.f;
#pragma unroll 4
            for (int cj = 0; cj < NCHUNK; ++cj) {
                float mc = cmax[h * NCHUNK + cj];
                float sc = (mc > -1e30f) ? __expf(mc - mh) : 0.f;
                denom += csum[h * NCHUNK + cj] * sc;
                o += o_part[((size_t)h * NCHUNK + cj) * D + tid] * sc;
            }
            attn_out[h * D + tid] = o / denom;
        }
    }
    grid_barrier(ctr2, flag2);

    // ================= phase 2: output GEMV (one row per block) ===============
    {
        int row = blockIdx.x;                 // 0..1279
        const float* Wrow = Wo + (size_t)row * E;
        float sum = 0.f;
#pragma unroll
        for (int i = 0; i < 5; ++i) {
            int idx = tid + 256 * i;
            sum += Wrow[idx] * attn_out[idx];
        }
#pragma unroll
        for (int off = 32; off > 0; off >>= 1) sum += __shfl_down(sum, off, 64);
        if (lane == 0) smax4[wave] = sum;
        __syncthreads();
        if (tid == 0)
            out[row] = smax4[0] + smax4[1] + smax4[2] + smax4[3] + bo[row];
    }
}

extern "C" void kernel_launch(void* const* d_in, const int* in_sizes, int n_in,
                              void* d_out, int out_size, void* d_ws, size_t ws_size,
                              hipStream_t stream) {
    const float* hs  = (const float*)d_in[0];
    const int*   pos = (const int*)d_in[1];    // int64 LE: low word ok (0<=pos<8192)
    const float* kc  = (const float*)d_in[2];
    const float* vc  = (const float*)d_in[3];
    const float* Wq  = (const float*)d_in[4];
    const float* bq  = (const float*)d_in[5];
    const float* Wk  = (const float*)d_in[6];
    const float* Wv  = (const float*)d_in[7];
    const float* bv  = (const float*)d_in[8];
    const float* Wo  = (const float*)d_in[9];
    const float* bo  = (const float*)d_in[10];

    float* out   = (float*)d_out;                 // [0 : E) attention output
    float* out_k = out + E;                       // new_k_cache (H*L*D)
    float* out_v = out_k + (size_t)H * L * D;     // new_v_cache

    unsigned* bar   = (unsigned*)d_ws;                // 1 KB barrier state
    float* fdata    = (float*)d_ws + 256;             // data region
    float* qkv      = fdata;                          // 3*E
    float* cmax     = qkv + 3 * E;                    // H*NCHUNK
    float* csum     = cmax + H * NCHUNK;              // H*NCHUNK
    float* o_part   = csum + H * NCHUNK;              // H*NCHUNK*D
    float* attn_out = o_part + (size_t)H * NCHUNK * D;  // E

    hipMemsetAsync(bar, 0, 1024, stream);             // reset barriers each call
    mega_kernel<<<NBLK, 256, 0, stream>>>(hs, Wq, bq, Wk, Wv, bv, Wo, bo,
                                          kc, vc, pos, bar, qkv, cmax, csum,
                                          o_part, attn_out, out, out_k, out_v);
}

// Round 8
// 53.999 us; speedup vs baseline: 16.8080x; 16.8080x over previous
//
#include <hip/hip_runtime.h>

#define E 1280
#define H 20
#define L 8192
#define D 64
#define CHUNK 256
#define NCHUNK (L / CHUNK)   // 32

// ---------------------------------------------------------------- K1: QKV GEMVs
// 3*E rows; one wave (64 lanes) per row; block = 256 = 4 rows.
__global__ void qkv_kernel(const float* __restrict__ hs,
                           const float* __restrict__ Wq, const float* __restrict__ bq,
                           const float* __restrict__ Wk,
                           const float* __restrict__ Wv, const float* __restrict__ bv,
                           float* __restrict__ qkv) {
    int row_global = blockIdx.x * 4 + (threadIdx.x >> 6);   // 0..3839
    int lane = threadIdx.x & 63;
    int mat = row_global / E;     // 0=q, 1=k, 2=v
    int row = row_global - mat * E;
    const float* W = (mat == 0) ? Wq : (mat == 1) ? Wk : Wv;
    const float4* Wrow = (const float4*)(W + (size_t)row * E);
    const float4* h4 = (const float4*)hs;
    float sum = 0.f;
#pragma unroll
    for (int i = 0; i < 5; ++i) {              // 320 float4 per row / 64 lanes
        int idx = lane + 64 * i;
        float4 w4 = Wrow[idx];
        float4 x4 = h4[idx];
        sum += w4.x * x4.x + w4.y * x4.y + w4.z * x4.z + w4.w * x4.w;
    }
#pragma unroll
    for (int off = 32; off > 0; off >>= 1) sum += __shfl_down(sum, off, 64);
    if (lane == 0) {
        float val;
        if (mat == 0)      val = (sum + bq[row]) * 0.125f;   // scale = 64^-0.5
        else if (mat == 1) val = sum;                        // k: no bias
        else               val = sum + bv[row];
        qkv[mat * E + row] = val;
    }
}

// ---------------------------------------------------------------- K2: fused K+V pass
// (exact R2 structure — measured best). grid = H*NCHUNK = 640 blocks of 256.
// Lane layout: rr = lane>>4, cc = lane&15 (16 lanes x float4 cover D=64).
__global__ void kv_kernel(const float* __restrict__ kc, const float* __restrict__ vc,
                          const float* __restrict__ qkv, const int* __restrict__ pos_p,
                          float* __restrict__ out_k, float* __restrict__ out_v,
                          float* __restrict__ cmax, float* __restrict__ csum,
                          float* __restrict__ o_part) {
    int h = blockIdx.x / NCHUNK;
    int c = blockIdx.x - h * NCHUNK;
    int pos = pos_p[0];
    int wave = threadIdx.x >> 6;
    int lane = threadIdx.x & 63;
    int rr = lane >> 4;
    int cc = lane & 15;

    __shared__ float s_lds[CHUNK];
    __shared__ float sacc[4][D];
    __shared__ float smax[4];
    __shared__ float spsum[4];

    float4 q4  = ((const float4*)qkv)[h * 16 + cc];
    float4 kn4 = ((const float4*)(qkv + E))[h * 16 + cc];
    float4 vn4 = ((const float4*)(qkv + 2 * E))[h * 16 + cc];

    size_t base = ((size_t)h * L + (size_t)c * CHUNK) * D;
    const float* kbase = kc + base;
    const float* vbase = vc + base;
    float* okbase = out_k + base;
    float* ovbase = out_v + base;
    int l0 = c * CHUNK;

    // ---- pass 1: K copy + scores
    float lmax = -INFINITY;
#pragma unroll 4
    for (int it = 0; it < CHUNK / 16; ++it) {
        int r = it * 16 + wave * 4 + rr;
        int l = l0 + r;
        float4 k4 = ((const float4*)(kbase + r * D))[cc];
        if (l == pos) k4 = kn4;
        ((float4*)(okbase + r * D))[cc] = k4;
        float p = q4.x * k4.x + q4.y * k4.y + q4.z * k4.z + q4.w * k4.w;
        p += __shfl_xor(p, 1, 16);
        p += __shfl_xor(p, 2, 16);
        p += __shfl_xor(p, 4, 16);
        p += __shfl_xor(p, 8, 16);
        float s = (l <= pos) ? p : -INFINITY;
        if (cc == 0) s_lds[r] = s;
        lmax = fmaxf(lmax, s);
    }
#pragma unroll
    for (int off = 32; off > 0; off >>= 1)
        lmax = fmaxf(lmax, __shfl_xor(lmax, off, 64));
    if (lane == 0) smax[wave] = lmax;
    __syncthreads();
    float m = fmaxf(fmaxf(smax[0], smax[1]), fmaxf(smax[2], smax[3]));

    // ---- pass 2: V copy + weighted accumulate (unnormalized, chunk-local max)
    float4 acc = {0.f, 0.f, 0.f, 0.f};
    float psum = 0.f;
#pragma unroll 4
    for (int it = 0; it < CHUNK / 16; ++it) {
        int r = it * 16 + wave * 4 + rr;
        int l = l0 + r;
        float4 v4 = ((const float4*)(vbase + r * D))[cc];
        if (l == pos) v4 = vn4;
        ((float4*)(ovbase + r * D))[cc] = v4;
        float p = (l <= pos) ? __expf(s_lds[r] - m) : 0.f;
        acc.x += p * v4.x; acc.y += p * v4.y; acc.z += p * v4.z; acc.w += p * v4.w;
        if (cc == 0) psum += p;
    }
    // reduce across rr groups (lanes ^16, ^32): cc lanes keep their d-slice
    acc.x += __shfl_xor(acc.x, 16, 64); acc.y += __shfl_xor(acc.y, 16, 64);
    acc.z += __shfl_xor(acc.z, 16, 64); acc.w += __shfl_xor(acc.w, 16, 64);
    acc.x += __shfl_xor(acc.x, 32, 64); acc.y += __shfl_xor(acc.y, 32, 64);
    acc.z += __shfl_xor(acc.z, 32, 64); acc.w += __shfl_xor(acc.w, 32, 64);
    psum += __shfl_xor(psum, 16, 64);
    psum += __shfl_xor(psum, 32, 64);
    if (rr == 0) {
        ((float4*)&sacc[wave][cc * 4])[0] = acc;
        if (cc == 0) spsum[wave] = psum;
    }
    __syncthreads();
    if (threadIdx.x < D) {            // final cross-wave sum + emit
        int d = threadIdx.x;
        float o = sacc[0][d] + sacc[1][d] + sacc[2][d] + sacc[3][d];
        o_part[((size_t)h * NCHUNK + c) * D + d] = o;
        if (d == 0) {
            cmax[h * NCHUNK + c] = m;
            csum[h * NCHUNK + c] = spsum[0] + spsum[1] + spsum[2] + spsum[3];
        }
    }
}

// ---------------------------------------------------------------- K3: combine + output GEMV
// 320 blocks x 256. Each block redundantly combines o_part (164 KB, L2-hot)
// into LDS attn_out[1280], then GEMVs its 4 Wo rows from LDS.
__global__ void combine_ogemv_kernel(const float* __restrict__ cmax,
                                     const float* __restrict__ csum,
                                     const float* __restrict__ o_part,
                                     const float* __restrict__ Wo,
                                     const float* __restrict__ bo,
                                     float* __restrict__ out) {
    __shared__ float s_attn[E];
    __shared__ float sred[4];
    int tid = threadIdx.x;

    // combine phase: outputs i = h*64+d, 5 per thread
#pragma unroll
    for (int i = tid; i < E; i += 256) {
        int h = i >> 6;
        int d = i & 63;
        float m = -INFINITY;
#pragma unroll
        for (int c = 0; c < NCHUNK; ++c) m = fmaxf(m, cmax[h * NCHUNK + c]);
        float denom = 0.f, o = 0.f;
#pragma unroll 4
        for (int c = 0; c < NCHUNK; ++c) {
            float mc = cmax[h * NCHUNK + c];
            float sc = (mc > -1e30f) ? __expf(mc - m) : 0.f;
            denom += csum[h * NCHUNK + c] * sc;
            o += o_part[((size_t)h * NCHUNK + c) * D + d] * sc;
        }
        s_attn[i] = o / denom;
    }
    __syncthreads();

    // GEMV phase: one row per wave
    int row = blockIdx.x * 4 + (tid >> 6);
    int lane = tid & 63;
    const float4* Wrow = (const float4*)(Wo + (size_t)row * E);
    const float4* a4p = (const float4*)s_attn;
    float sum = 0.f;
#pragma unroll
    for (int i = 0; i < 5; ++i) {
        int idx = lane + 64 * i;
        float4 w4 = Wrow[idx];
        float4 a4 = a4p[idx];
        sum += w4.x * a4.x + w4.y * a4.y + w4.z * a4.z + w4.w * a4.w;
    }
#pragma unroll
    for (int off = 32; off > 0; off >>= 1) sum += __shfl_down(sum, off, 64);
    if (lane == 0) out[row] = sum + bo[row];
}

extern "C" void kernel_launch(void* const* d_in, const int* in_sizes, int n_in,
                              void* d_out, int out_size, void* d_ws, size_t ws_size,
                              hipStream_t stream) {
    const float* hs  = (const float*)d_in[0];
    const int*   pos = (const int*)d_in[1];    // int64 LE: low word ok (0<=pos<8192)
    const float* kc  = (const float*)d_in[2];
    const float* vc  = (const float*)d_in[3];
    const float* Wq  = (const float*)d_in[4];
    const float* bq  = (const float*)d_in[5];
    const float* Wk  = (const float*)d_in[6];
    const float* Wv  = (const float*)d_in[7];
    const float* bv  = (const float*)d_in[8];
    const float* Wo  = (const float*)d_in[9];
    const float* bo  = (const float*)d_in[10];

    float* out   = (float*)d_out;                 // [0 : E) attention output
    float* out_k = out + E;                       // new_k_cache (H*L*D)
    float* out_v = out_k + (size_t)H * L * D;     // new_v_cache

    float* ws       = (float*)d_ws;
    float* qkv      = ws;                             // 3*E
    float* cmax     = qkv + 3 * E;                    // H*NCHUNK
    float* csum     = cmax + H * NCHUNK;              // H*NCHUNK
    float* o_part   = csum + H * NCHUNK;              // H*NCHUNK*D

    qkv_kernel<<<3 * E / 4, 256, 0, stream>>>(hs, Wq, bq, Wk, Wv, bv, qkv);
    kv_kernel<<<H * NCHUNK, 256, 0, stream>>>(kc, vc, qkv, pos, out_k, out_v,
                                              cmax, csum, o_part);
    combine_ogemv_kernel<<<E / 4, 256, 0, stream>>>(cmax, csum, o_part, Wo, bo, out);
}

// Round 9
// 53.832 us; speedup vs baseline: 16.8602x; 1.0031x over previous
//
#include <hip/hip_runtime.h>

#define E 1280
#define H 20
#define L 8192
#define D 64
#define WCHUNK 64                 // rows per wave
#define NCH (L / WCHUNK)          // 128 chunks per head
#define BLOCKS_PER_HEAD (L / 256) // 32 (4 waves per block)

// ---------------------------------------------------------------- K1: QKV GEMVs
// 3*E rows; one wave per row; block = 256 = 4 rows.
__global__ void qkv_kernel(const float* __restrict__ hs,
                           const float* __restrict__ Wq, const float* __restrict__ bq,
                           const float* __restrict__ Wk,
                           const float* __restrict__ Wv, const float* __restrict__ bv,
                           float* __restrict__ qkv) {
    int row_global = blockIdx.x * 4 + (threadIdx.x >> 6);   // 0..3839
    int lane = threadIdx.x & 63;
    int mat = row_global / E;     // 0=q, 1=k, 2=v
    int row = row_global - mat * E;
    const float* W = (mat == 0) ? Wq : (mat == 1) ? Wk : Wv;
    const float4* Wrow = (const float4*)(W + (size_t)row * E);
    const float4* h4 = (const float4*)hs;
    float sum = 0.f;
#pragma unroll
    for (int i = 0; i < 5; ++i) {
        int idx = lane + 64 * i;
        float4 w4 = Wrow[idx];
        float4 x4 = h4[idx];
        sum += w4.x * x4.x + w4.y * x4.y + w4.z * x4.z + w4.w * x4.w;
    }
#pragma unroll
    for (int off = 32; off > 0; off >>= 1) sum += __shfl_down(sum, off, 64);
    if (lane == 0) {
        float val;
        if (mat == 0)      val = (sum + bq[row]) * 0.125f;   // scale = 64^-0.5
        else if (mat == 1) val = sum;                        // k: no bias
        else               val = sum + bv[row];
        qkv[mat * E + row] = val;
    }
}

// ---------------------------------------------------------------- K2: barrier-free K+V
// grid = 640 blocks x 256; each WAVE autonomously owns 64 rows of one head.
// No __syncthreads, no LDS staging. Lane = rr*16+cc: cc = d-slice (float4),
// rr = row-in-group. Butterfly shfl leaves full row-score in all 16 cc lanes.
__global__ void kv_kernel(const float* __restrict__ kc, const float* __restrict__ vc,
                          const float* __restrict__ qkv, const int* __restrict__ pos_p,
                          float* __restrict__ out_k, float* __restrict__ out_v,
                          float* __restrict__ cmax, float* __restrict__ csum,
                          float* __restrict__ o_part) {
    int blk = blockIdx.x;                       // 0..639
    int h = blk / BLOCKS_PER_HEAD;
    int cb = blk - h * BLOCKS_PER_HEAD;         // 0..31
    int wave = threadIdx.x >> 6;
    int lane = threadIdx.x & 63;
    int rr = lane >> 4;
    int cc = lane & 15;
    int chunk = cb * 4 + wave;                  // 0..127 within head
    int l0 = chunk * WCHUNK;
    int pos = pos_p[0];

    float4 q4  = ((const float4*)qkv)[h * 16 + cc];
    float4 kn4 = ((const float4*)(qkv + E))[h * 16 + cc];
    float4 vn4 = ((const float4*)(qkv + 2 * E))[h * 16 + cc];

    size_t base = ((size_t)h * L + l0) * D;
    const float* kbase = kc + base;
    const float* vbase = vc + base;
    float* okbase = out_k + base;
    float* ovbase = out_v + base;

    // ---- pass 1: stream K, copy, scores into registers
    float sc[16];
#pragma unroll
    for (int it = 0; it < 16; ++it) {
        int r = it * 4 + rr;                    // 0..63
        int l = l0 + r;
        float4 k4 = ((const float4*)(kbase + r * D))[cc];
        if (l == pos) k4 = kn4;
        ((float4*)(okbase + r * D))[cc] = k4;
        float p = k4.x * q4.x + k4.y * q4.y + k4.z * q4.z + k4.w * q4.w;
        p += __shfl_xor(p, 1, 64);
        p += __shfl_xor(p, 2, 64);
        p += __shfl_xor(p, 4, 64);
        p += __shfl_xor(p, 8, 64);              // all 16 cc lanes hold row sum
        sc[it] = (l <= pos) ? p : -INFINITY;
    }

    // ---- wave max (registers + 2 shfls)
    float m = sc[0];
#pragma unroll
    for (int it = 1; it < 16; ++it) m = fmaxf(m, sc[it]);
    m = fmaxf(m, __shfl_xor(m, 16, 64));
    m = fmaxf(m, __shfl_xor(m, 32, 64));

    // ---- weights + partial sum
    float psum = 0.f;
#pragma unroll
    for (int it = 0; it < 16; ++it) {
        float w = (sc[it] > -1e30f) ? __expf(sc[it] - m) : 0.f;
        sc[it] = w;
        psum += w;
    }
    psum += __shfl_xor(psum, 16, 64);
    psum += __shfl_xor(psum, 32, 64);           // total over the wave's 64 rows

    // ---- pass 2: stream V, copy, weighted accumulate
    float4 acc = {0.f, 0.f, 0.f, 0.f};
#pragma unroll
    for (int it = 0; it < 16; ++it) {
        int r = it * 4 + rr;
        int l = l0 + r;
        float4 v4 = ((const float4*)(vbase + r * D))[cc];
        if (l == pos) v4 = vn4;
        ((float4*)(ovbase + r * D))[cc] = v4;
        float w = sc[it];
        acc.x += w * v4.x; acc.y += w * v4.y; acc.z += w * v4.z; acc.w += w * v4.w;
    }
    acc.x += __shfl_xor(acc.x, 16, 64); acc.y += __shfl_xor(acc.y, 16, 64);
    acc.z += __shfl_xor(acc.z, 16, 64); acc.w += __shfl_xor(acc.w, 16, 64);
    acc.x += __shfl_xor(acc.x, 32, 64); acc.y += __shfl_xor(acc.y, 32, 64);
    acc.z += __shfl_xor(acc.z, 32, 64); acc.w += __shfl_xor(acc.w, 32, 64);

    // ---- emit per-wave partials (no sync needed)
    if (rr == 0) {
        float* op = o_part + ((size_t)h * NCH + chunk) * WCHUNK;
        ((float4*)op)[cc] = acc;
    }
    if (lane == 0) {
        cmax[h * NCH + chunk] = m;
        csum[h * NCH + chunk] = psum;
    }
}

// ---------------------------------------------------------------- K3: cross-chunk combine
// H blocks x 256: d = tid&63, cg = tid>>6 owns 32 of the 128 chunks.
__global__ void combine_kernel(const float* __restrict__ cmax, const float* __restrict__ csum,
                               const float* __restrict__ o_part, float* __restrict__ attn_out) {
    int h = blockIdx.x;
    int tid = threadIdx.x;
    int d = tid & 63;
    int cg = tid >> 6;
    __shared__ float so[4][D];
    __shared__ float sden[4];

    float m = -INFINITY;
#pragma unroll 8
    for (int c = 0; c < NCH; ++c) m = fmaxf(m, cmax[h * NCH + c]);

    float denom = 0.f, o = 0.f;
#pragma unroll 4
    for (int c = cg * 32; c < cg * 32 + 32; ++c) {
        float mc = cmax[h * NCH + c];
        float sf = (mc > -1e30f) ? __expf(mc - m) : 0.f;
        denom += csum[h * NCH + c] * sf;
        o += o_part[((size_t)h * NCH + c) * WCHUNK + d] * sf;
    }
    so[cg][d] = o;
    if (d == 0) sden[cg] = denom;
    __syncthreads();
    if (cg == 0)
        attn_out[h * D + d] = (so[0][d] + so[1][d] + so[2][d] + so[3][d]) /
                              (sden[0] + sden[1] + sden[2] + sden[3]);
}

// ---------------------------------------------------------------- K4: output GEMV
__global__ void ogemv_kernel(const float* __restrict__ attn_out, const float* __restrict__ Wo,
                             const float* __restrict__ bo, float* __restrict__ out) {
    int row = blockIdx.x * 4 + (threadIdx.x >> 6);
    int lane = threadIdx.x & 63;
    const float4* Wrow = (const float4*)(Wo + (size_t)row * E);
    const float4* x4 = (const float4*)attn_out;
    float sum = 0.f;
#pragma unroll
    for (int i = 0; i < 5; ++i) {
        int idx = lane + 64 * i;
        float4 w4 = Wrow[idx];
        float4 a4 = x4[idx];
        sum += w4.x * a4.x + w4.y * a4.y + w4.z * a4.z + w4.w * a4.w;
    }
#pragma unroll
    for (int off = 32; off > 0; off >>= 1) sum += __shfl_down(sum, off, 64);
    if (lane == 0) out[row] = sum + bo[row];
}

extern "C" void kernel_launch(void* const* d_in, const int* in_sizes, int n_in,
                              void* d_out, int out_size, void* d_ws, size_t ws_size,
                              hipStream_t stream) {
    const float* hs  = (const float*)d_in[0];
    const int*   pos = (const int*)d_in[1];    // int64 LE: low word ok (0<=pos<8192)
    const float* kc  = (const float*)d_in[2];
    const float* vc  = (const float*)d_in[3];
    const float* Wq  = (const float*)d_in[4];
    const float* bq  = (const float*)d_in[5];
    const float* Wk  = (const float*)d_in[6];
    const float* Wv  = (const float*)d_in[7];
    const float* bv  = (const float*)d_in[8];
    const float* Wo  = (const float*)d_in[9];
    const float* bo  = (const float*)d_in[10];

    float* out   = (float*)d_out;                 // [0 : E) attention output
    float* out_k = out + E;                       // new_k_cache (H*L*D)
    float* out_v = out_k + (size_t)H * L * D;     // new_v_cache

    float* ws       = (float*)d_ws;
    float* qkv      = ws;                             // 3*E
    float* cmax     = qkv + 3 * E;                    // H*NCH
    float* csum     = cmax + H * NCH;                 // H*NCH
    float* o_part   = csum + H * NCH;                 // H*NCH*64
    float* attn_out = o_part + (size_t)H * NCH * WCHUNK;  // E

    qkv_kernel<<<3 * E / 4, 256, 0, stream>>>(hs, Wq, bq, Wk, Wv, bv, qkv);
    kv_kernel<<<H * BLOCKS_PER_HEAD, 256, 0, stream>>>(kc, vc, qkv, pos, out_k, out_v,
                                                       cmax, csum, o_part);
    combine_kernel<<<H, 256, 0, stream>>>(cmax, csum, o_part, attn_out);
    ogemv_kernel<<<E / 4, 256, 0, stream>>>(attn_out, Wo, bo, out);
}

// Round 10
// 43.269 us; speedup vs baseline: 20.9759x; 1.2441x over previous
//
#include <hip/hip_runtime.h>

#define E 1280
#define H 20
#define L 8192
#define D 64
#define CHUNK 256
#define NCHUNK (L / CHUNK)   // 32

// ---------------------------------------------------------------- K1: QKV GEMVs
// 3*E rows; one wave (64 lanes) per row; block = 256 = 4 rows.
__global__ void qkv_kernel(const float* __restrict__ hs,
                           const float* __restrict__ Wq, const float* __restrict__ bq,
                           const float* __restrict__ Wk,
                           const float* __restrict__ Wv, const float* __restrict__ bv,
                           float* __restrict__ qkv) {
    int row_global = blockIdx.x * 4 + (threadIdx.x >> 6);   // 0..3839
    int lane = threadIdx.x & 63;
    int mat = row_global / E;     // 0=q, 1=k, 2=v
    int row = row_global - mat * E;
    const float* W = (mat == 0) ? Wq : (mat == 1) ? Wk : Wv;
    const float4* Wrow = (const float4*)(W + (size_t)row * E);
    const float4* h4 = (const float4*)hs;
    float sum = 0.f;
#pragma unroll
    for (int i = 0; i < 5; ++i) {              // 320 float4 per row / 64 lanes
        int idx = lane + 64 * i;
        float4 w4 = Wrow[idx];
        float4 x4 = h4[idx];
        sum += w4.x * x4.x + w4.y * x4.y + w4.z * x4.z + w4.w * x4.w;
    }
#pragma unroll
    for (int off = 32; off > 0; off >>= 1) sum += __shfl_down(sum, off, 64);
    if (lane == 0) {
        float val;
        if (mat == 0)      val = (sum + bq[row]) * 0.125f;   // scale = 64^-0.5
        else if (mat == 1) val = sum;                        // k: no bias
        else               val = sum + bv[row];
        qkv[mat * E + row] = val;
    }
}

// ---------------------------------------------------------------- K2: fused K+V pass
// grid = H*NCHUNK blocks of 256 (4 waves). Lane layout: rr = lane>>4 (row in
// group of 4), cc = lane&15 (16 lanes x float4 cover D=64).
// Pass 1: read K chunk (sub k_new at pos), write new_k_cache, scores -> LDS,
//         block max. Pass 2: read V chunk (sub v_new), write new_v_cache,
//         accumulate exp(s-m)*V and sum(exp). Emit per-chunk m, sum, o[64].
__global__ void kv_kernel(const float* __restrict__ kc, const float* __restrict__ vc,
                          const float* __restrict__ qkv, const int* __restrict__ pos_p,
                          float* __restrict__ out_k, float* __restrict__ out_v,
                          float* __restrict__ cmax, float* __restrict__ csum,
                          float* __restrict__ o_part) {
    int h = blockIdx.x / NCHUNK;
    int c = blockIdx.x - h * NCHUNK;
    int pos = pos_p[0];
    int wave = threadIdx.x >> 6;
    int lane = threadIdx.x & 63;
    int rr = lane >> 4;
    int cc = lane & 15;

    __shared__ float s_lds[CHUNK];
    __shared__ float sacc[4][D];
    __shared__ float smax[4];
    __shared__ float spsum[4];

    float4 q4  = ((const float4*)qkv)[h * 16 + cc];
    float4 kn4 = ((const float4*)(qkv + E))[h * 16 + cc];
    float4 vn4 = ((const float4*)(qkv + 2 * E))[h * 16 + cc];

    size_t base = ((size_t)h * L + (size_t)c * CHUNK) * D;
    const float* kbase = kc + base;
    const float* vbase = vc + base;
    float* okbase = out_k + base;
    float* ovbase = out_v + base;
    int l0 = c * CHUNK;

    // ---- pass 1: K copy + scores
    float lmax = -INFINITY;
#pragma unroll 4
    for (int it = 0; it < CHUNK / 16; ++it) {
        int r = it * 16 + wave * 4 + rr;
        int l = l0 + r;
        float4 k4 = ((const float4*)(kbase + r * D))[cc];
        if (l == pos) k4 = kn4;
        ((float4*)(okbase + r * D))[cc] = k4;
        float p = q4.x * k4.x + q4.y * k4.y + q4.z * k4.z + q4.w * k4.w;
        p += __shfl_xor(p, 1, 16);
        p += __shfl_xor(p, 2, 16);
        p += __shfl_xor(p, 4, 16);
        p += __shfl_xor(p, 8, 16);
        float s = (l <= pos) ? p : -INFINITY;
        if (cc == 0) s_lds[r] = s;
        lmax = fmaxf(lmax, s);
    }
#pragma unroll
    for (int off = 32; off > 0; off >>= 1)
        lmax = fmaxf(lmax, __shfl_xor(lmax, off, 64));
    if (lane == 0) smax[wave] = lmax;
    __syncthreads();
    float m = fmaxf(fmaxf(smax[0], smax[1]), fmaxf(smax[2], smax[3]));

    // ---- pass 2: V copy + weighted accumulate (unnormalized, chunk-local max)
    float4 acc = {0.f, 0.f, 0.f, 0.f};
    float psum = 0.f;
#pragma unroll 4
    for (int it = 0; it < CHUNK / 16; ++it) {
        int r = it * 16 + wave * 4 + rr;
        int l = l0 + r;
        float4 v4 = ((const float4*)(vbase + r * D))[cc];
        if (l == pos) v4 = vn4;
        ((float4*)(ovbase + r * D))[cc] = v4;
        float p = (l <= pos) ? __expf(s_lds[r] - m) : 0.f;
        acc.x += p * v4.x; acc.y += p * v4.y; acc.z += p * v4.z; acc.w += p * v4.w;
        if (cc == 0) psum += p;
    }
    // reduce across rr groups (lanes ^16, ^32): cc lanes keep their d-slice
    acc.x += __shfl_xor(acc.x, 16, 64); acc.y += __shfl_xor(acc.y, 16, 64);
    acc.z += __shfl_xor(acc.z, 16, 64); acc.w += __shfl_xor(acc.w, 16, 64);
    acc.x += __shfl_xor(acc.x, 32, 64); acc.y += __shfl_xor(acc.y, 32, 64);
    acc.z += __shfl_xor(acc.z, 32, 64); acc.w += __shfl_xor(acc.w, 32, 64);
    psum += __shfl_xor(psum, 16, 64);
    psum += __shfl_xor(psum, 32, 64);
    if (rr == 0) {
        ((float4*)&sacc[wave][cc * 4])[0] = acc;
        if (cc == 0) spsum[wave] = psum;
    }
    __syncthreads();
    if (threadIdx.x < D) {            // wave 0: final cross-wave sum + emit
        int d = threadIdx.x;
        float o = sacc[0][d] + sacc[1][d] + sacc[2][d] + sacc[3][d];
        o_part[((size_t)h * NCHUNK + c) * D + d] = o;
        if (d == 0) {
            cmax[h * NCHUNK + c] = m;
            csum[h * NCHUNK + c] = spsum[0] + spsum[1] + spsum[2] + spsum[3];
        }
    }
}

// ---------------------------------------------------------------- K3: cross-chunk combine
__global__ void combine_kernel(const float* __restrict__ cmax, const float* __restrict__ csum,
                               const float* __restrict__ o_part, float* __restrict__ attn_out) {
    int h = blockIdx.x;
    int d = threadIdx.x;              // 64 threads
    float m = -INFINITY;
#pragma unroll
    for (int c = 0; c < NCHUNK; ++c) m = fmaxf(m, cmax[h * NCHUNK + c]);
    float denom = 0.f, o = 0.f;
#pragma unroll 4
    for (int c = 0; c < NCHUNK; ++c) {
        float mc = cmax[h * NCHUNK + c];
        float sc = (mc > -1e30f) ? __expf(mc - m) : 0.f;
        denom += csum[h * NCHUNK + c] * sc;
        o += o_part[((size_t)h * NCHUNK + c) * D + d] * sc;
    }
    attn_out[h * D + d] = o / denom;
}

// ---------------------------------------------------------------- K4: output GEMV
__global__ void ogemv_kernel(const float* __restrict__ attn_out, const float* __restrict__ Wo,
                             const float* __restrict__ bo, float* __restrict__ out) {
    int row = blockIdx.x * 4 + (threadIdx.x >> 6);
    int lane = threadIdx.x & 63;
    const float4* Wrow = (const float4*)(Wo + (size_t)row * E);
    const float4* x4 = (const float4*)attn_out;
    float sum = 0.f;
#pragma unroll
    for (int i = 0; i < 5; ++i) {
        int idx = lane + 64 * i;
        float4 w4 = Wrow[idx];
        float4 a4 = x4[idx];
        sum += w4.x * a4.x + w4.y * a4.y + w4.z * a4.z + w4.w * a4.w;
    }
#pragma unroll
    for (int off = 32; off > 0; off >>= 1) sum += __shfl_down(sum, off, 64);
    if (lane == 0) out[row] = sum + bo[row];
}

extern "C" void kernel_launch(void* const* d_in, const int* in_sizes, int n_in,
                              void* d_out, int out_size, void* d_ws, size_t ws_size,
                              hipStream_t stream) {
    const float* hs  = (const float*)d_in[0];
    const int*   pos = (const int*)d_in[1];    // int64 little-endian: low word ok (0<=pos<8192)
    const float* kc  = (const float*)d_in[2];
    const float* vc  = (const float*)d_in[3];
    const float* Wq  = (const float*)d_in[4];
    const float* bq  = (const float*)d_in[5];
    const float* Wk  = (const float*)d_in[6];
    const float* Wv  = (const float*)d_in[7];
    const float* bv  = (const float*)d_in[8];
    const float* Wo  = (const float*)d_in[9];
    const float* bo  = (const float*)d_in[10];

    float* out   = (float*)d_out;                 // [0 : E)        attention output
    float* out_k = out + E;                       // new_k_cache  (H*L*D)
    float* out_v = out_k + (size_t)H * L * D;     // new_v_cache

    float* ws       = (float*)d_ws;
    float* qkv      = ws;                             // 3*E
    float* cmax     = qkv + 3 * E;                    // H*NCHUNK
    float* csum     = cmax + H * NCHUNK;              // H*NCHUNK
    float* o_part   = csum + H * NCHUNK;              // H*NCHUNK*D
    float* attn_out = o_part + (size_t)H * NCHUNK * D;  // E

    qkv_kernel<<<3 * E / 4, 256, 0, stream>>>(hs, Wq, bq, Wk, Wv, bv, qkv);
    kv_kernel<<<H * NCHUNK, 256, 0, stream>>>(kc, vc, qkv, pos, out_k, out_v,
                                              cmax, csum, o_part);
    combine_kernel<<<H, 64, 0, stream>>>(cmax, csum, o_part, attn_out);
    ogemv_kernel<<<E / 4, 256, 0, stream>>>(attn_out, Wo, bo, out);
}